// Round 7
// baseline (134.033 us; speedup 1.0000x reference)
//
#include <hip/hip_runtime.h>

#define BATCH 16384
#define LAYERS 63
#define BM 128
#define XS 72              // Hs row stride in bf16: 144 B
#define BLOB_BYTES 21504   // W1 8192 | W2 8192 | W3 4096 | b1 256 | b2 256 | b3 128 | pad
#define LDS_OFF 8192       // W1 goes global->VGPR; LDS images [8192, 21504)
#define LDS_BYTES 13312

typedef float f4 __attribute__((ext_vector_type(4)));
typedef short s8 __attribute__((ext_vector_type(8)));          // 8 x bf16
typedef unsigned int u4 __attribute__((ext_vector_type(4)));   // same 16 B as s8

__device__ __forceinline__ float rcpf(float v) { return __builtin_amdgcn_rcpf(v); }

__device__ __forceinline__ float fast_tanh(float v) {   // 1 exp + 1 rcp + 3 VALU
    float e = __expf(2.f * v);
    return 1.f - 2.f * rcpf(e + 1.f);
}
__device__ __forceinline__ float softplus_f(float v) {
    return fmaxf(v, 0.f) + __logf(1.f + __expf(-fabsf(v)));
}
__device__ __forceinline__ unsigned short f2bf(float f) {   // RNE fp32->bf16
    unsigned int u = __float_as_uint(f);
    u += 0x7fffu + ((u >> 16) & 1u);
    return (unsigned short)(u >> 16);
}
#if __has_builtin(__builtin_amdgcn_cvt_pk_bf16_f32)
__device__ __forceinline__ unsigned pk2(float a, float b) {   // gfx950 packed cvt
    auto r = __builtin_amdgcn_cvt_pk_bf16_f32(a, b);
    return __builtin_bit_cast(unsigned, r);
}
#else
__device__ __forceinline__ unsigned pk2(float a, float b) {
    return (unsigned)f2bf(a) | ((unsigned)f2bf(b) << 16);
}
#endif
__device__ __forceinline__ unsigned long long pack4(float a, float b, float c, float d) {
    return (unsigned long long)pk2(a, b) | ((unsigned long long)pk2(c, d) << 32);
}

// RQS spline for one (b,d). Semantics verified vs reference rounds 1-6.
// Divisions -> v_rcp; derivatives: select raw param, then 2 double-softplus.
__device__ __forceinline__ void rqs_eval(const float* p, float xv, float& zout, float& ldout) {
    const bool inside = (xv >= -3.f) && (xv <= 3.f);
    const float xi = fminf(fmaxf(xv, -3.f), 3.f);

    float wa[8], ha[8];
    {   // widths = affine(softmax(6*softmax(p[0:8]))) — no max-sub (range-safe)
        float s = 0.f;
        #pragma unroll
        for (int i = 0; i < 8; i++) { wa[i] = __expf(p[i]); s += wa[i]; }
        float inv = 6.f * rcpf(s);
        #pragma unroll
        for (int i = 0; i < 8; i++) wa[i] *= inv;
        s = 0.f;
        #pragma unroll
        for (int i = 0; i < 8; i++) { wa[i] = __expf(wa[i]); s += wa[i]; }
        inv = 0.992f * rcpf(s);
        #pragma unroll
        for (int i = 0; i < 8; i++) wa[i] = 1e-3f + wa[i] * inv;
    }
    {
        float s = 0.f;
        #pragma unroll
        for (int i = 0; i < 8; i++) { ha[i] = __expf(p[8 + i]); s += ha[i]; }
        float inv = 6.f * rcpf(s);
        #pragma unroll
        for (int i = 0; i < 8; i++) ha[i] *= inv;
        s = 0.f;
        #pragma unroll
        for (int i = 0; i < 8; i++) { ha[i] = __expf(ha[i]); s += ha[i]; }
        inv = 0.992f * rcpf(s);
        #pragma unroll
        for (int i = 0; i < 8; i++) ha[i] = 1e-3f + ha[i] * inv;
    }

    float cw[9], ch[9];
    cw[0] = -3.f; ch[0] = -3.f;
    {
        float cs = 0.f, hs = 0.f;
        #pragma unroll
        for (int k = 1; k < 8; k++) {
            cs += wa[k - 1]; cw[k] = 6.f * cs - 3.f;
            hs += ha[k - 1]; ch[k] = 6.f * hs - 3.f;
        }
    }
    cw[8] = 3.f; ch[8] = 3.f;

    int cnt = 0;
    #pragma unroll
    for (int k = 0; k < 8; k++) cnt += (xi >= cw[k]) ? 1 : 0;
    cnt += (xi >= 3.000001f) ? 1 : 0;
    const int bin = min(max(cnt - 1, 0), 7);

    float in_cw = 0.f, in_w = 1.f, in_ch = 0.f, in_h = 1.f;
    float pd0 = 0.f, pd1 = 0.f;
    #pragma unroll
    for (int k = 0; k < 8; k++)
        if (k == bin) {
            in_cw = cw[k]; in_w = cw[k + 1] - cw[k];
            in_ch = ch[k]; in_h = ch[k + 1] - ch[k];
            if (k >= 1) pd0 = p[15 + k];
            if (k <= 6) pd1 = p[16 + k];
        }
    // boundary derivs: 1e-3 + softplus(log(exp(1-1e-3)-1)) == 1.0 exactly
    const float dk  = (bin == 0) ? 1.f : 1e-3f + softplus_f(softplus_f(pd0));
    const float dk1 = (bin == 7) ? 1.f : 1e-3f + softplus_f(softplus_f(pd1));

    const float rw    = rcpf(in_w);
    const float delta = in_h * rw;
    const float th    = (xi - in_cw) * rw;
    const float omt = 1.f - th;
    const float t1  = th * omt;
    const float th2 = th * th;
    const float numer = in_h * (delta * th2 + dk * t1);
    const float denom = delta + (dk + dk1 - 2.f * delta) * t1;
    const float outv  = in_ch + numer * rcpf(denom);
    const float dnum  = delta * delta * (dk1 * th2 + 2.f * delta * t1 + dk * omt * omt);
    const float ldv = __logf(dnum) - 2.f * __logf(denom);

    zout  = inside ? outv : xv;
    ldout = inside ? ldv : 0.f;
}

// Prep: weights -> per-layer swizzled bf16 blob (63 blocks, nothing else).
__global__ __launch_bounds__(256) void prep_kernel(
    const float* __restrict__ W1, const float* __restrict__ W2, const float* __restrict__ W3,
    const float* __restrict__ b1, const float* __restrict__ b2, const float* __restrict__ b3,
    unsigned char* __restrict__ blobG)
{
    const int tid = threadIdx.x;
    const int l = blockIdx.x;
    unsigned char* gb = blobG + (size_t)l * BLOB_BYTES;
    for (int e = tid; e < 1024; e += 256) {     // W1|W2: (m, row r, block j), XOR-8 swizzle
        int m = e >> 9, r = (e >> 3) & 63, j = e & 7;
        const float* src = (m ? W2 : W1) + (size_t)l * 4096 + r * 64 + j * 8;
        unsigned long long lo = pack4(src[0], src[1], src[2], src[3]);
        unsigned long long hi = pack4(src[4], src[5], src[6], src[7]);
        unsigned long long* dst = (unsigned long long*)(gb + m * 8192 + r * 128 + ((j ^ (r & 7)) << 4));
        dst[0] = lo; dst[1] = hi;
    }
    if (tid < 256) {                            // W3 padded to 32 rows
        int r = tid >> 3, j = tid & 7;
        unsigned long long lo = 0ull, hi = 0ull;
        if (r < 23) {
            const float* src = W3 + (size_t)l * 1472 + r * 64 + j * 8;
            lo = pack4(src[0], src[1], src[2], src[3]);
            hi = pack4(src[4], src[5], src[6], src[7]);
        }
        unsigned long long* dst = (unsigned long long*)(gb + 16384 + r * 128 + ((j ^ (r & 7)) << 4));
        dst[0] = lo; dst[1] = hi;
    }
    if (tid < 64)        *(float*)(gb + 20480 + tid * 4)         = b1[l * 64 + tid];
    else if (tid < 128)  *(float*)(gb + 20736 + (tid - 64) * 4)  = b2[l * 64 + tid - 64];
    else if (tid < 160)  *(float*)(gb + 20992 + (tid - 128) * 4) = (tid - 128 < 23) ? b3[l * 23 + tid - 128] : 0.f;
    else                 { int e = tid - 160; if (e < 96) *(float*)(gb + 21120 + e * 4) = 0.f; }
}

// Grid (128, 64): y=0..62 -> one layer x one 128-row tile; y=63 -> d=0 spline
// tiles. X B-frags converted f32->bf16 in-register (no x_bf pass). W1 A-frags
// in VGPRs from L2-resident blob; W2/W3/biases via global_load_lds (13 KB).
// ld zeroed by memset; every contributor (incl. d0) uses unsafeAtomicAdd.
__global__ __launch_bounds__(256, 5) void mlp_rqs_kernel(
    const float* __restrict__ x, const float* __restrict__ init_param,
    const unsigned char* __restrict__ blobG,
    float* __restrict__ z, float* __restrict__ ld)
{
    const int l = blockIdx.y;
    const int tid = threadIdx.x;

    if (l == LAYERS) {   // d = 0 column: params are init_param for every row
        if (tid < 128) {
            const int row = blockIdx.x * 128 + tid;
            float p[23];
            #pragma unroll
            for (int j = 0; j < 23; j++) p[j] = init_param[j];
            float zv, lv;
            rqs_eval(p, x[(size_t)row * 64], zv, lv);
            z[(size_t)row * 64] = zv;
            unsafeAtomicAdd(ld + row, lv);
        }
        return;
    }

    const int keff = l + 1;
    const int b0 = blockIdx.x * BM;
    const int ln = tid & 63, wv = tid >> 6;
    const int c = ln & 15, q = ln >> 4;
    const int mbase = wv * 32;
    const int c7 = c & 7;

    __shared__ __align__(16) unsigned char blob[LDS_BYTES];
    __shared__ __align__(16) unsigned short Hs[BM * XS];

    unsigned short* W2s = (unsigned short*)blob;            // rows 0..63, swizzled
    unsigned short* W3s = (unsigned short*)(blob + 8192);   // rows 0..31, swizzled
    const float* b1s = (const float*)(blob + 12288);
    const float* b2s = (const float*)(blob + 12544);
    const float* b3s = (const float*)(blob + 12800);
    float* PsF = (float*)Hs;   // Ps row r: 24 floats at word r*36 (overlay, h2 dead)

    const unsigned char* gblob = blobG + (size_t)l * BLOB_BYTES;

    // ---- async DMA: W2|W3|biases (13 KB), once per block ----
    for (int t = wv; t < 13; t += 4)
        __builtin_amdgcn_global_load_lds(
            (const __attribute__((address_space(1))) void*)(gblob + LDS_OFF + t * 1024 + ln * 16),
            (__attribute__((address_space(3))) void*)(blob + t * 1024 + ln * 16), 16, 0, 0);

    const int ks1 = (keff + 31) >> 5;     // 1 or 2

    // ---- W1 A-frags -> VGPR (swizzled image, L2-hot) ----
    s8 aw1[2][4];
    #pragma unroll
    for (int mt = 0; mt < 4; mt++)
        aw1[0][mt] = *(const s8*)(gblob + (mt * 16 + c) * 128 + ((q ^ c7) << 4));
    if (ks1 == 2) {
        #pragma unroll
        for (int mt = 0; mt < 4; mt++)
            aw1[1][mt] = *(const s8*)(gblob + (mt * 16 + c) * 128 + (((4 + q) ^ c7) << 4));
    }

    // ---- X B-frags straight from f32 x, converted + tril-masked in-register ----
    u4 B0u, B1u, B2u{}, B3u{};
    {
        const float* xr = x + (size_t)(b0 + mbase + c) * 64 + q * 8;
        f4 v0a = *(const f4*)xr,            v0b = *(const f4*)(xr + 4);
        f4 v1a = *(const f4*)(xr + 1024),   v1b = *(const f4*)(xr + 1028);
        B0u = u4{pk2(v0a[0], v0a[1]), pk2(v0a[2], v0a[3]), pk2(v0b[0], v0b[1]), pk2(v0b[2], v0b[3])};
        B1u = u4{pk2(v1a[0], v1a[1]), pk2(v1a[2], v1a[3]), pk2(v1b[0], v1b[1]), pk2(v1b[2], v1b[3])};
        if (ks1 == 2) {
            f4 w0a = *(const f4*)(xr + 32),        w0b = *(const f4*)(xr + 36);
            f4 w1a = *(const f4*)(xr + 1024 + 32), w1b = *(const f4*)(xr + 1024 + 36);
            B2u = u4{pk2(w0a[0], w0a[1]), pk2(w0a[2], w0a[3]), pk2(w0b[0], w0b[1]), pk2(w0b[2], w0b[3])};
            B3u = u4{pk2(w1a[0], w1a[1]), pk2(w1a[2], w1a[3]), pk2(w1b[0], w1b[1]), pk2(w1b[2], w1b[3])};
        }
        const int n = keff - ((ks1 - 1) * 32 + q * 8);   // valid elems in boundary chunk
        unsigned mk[4];
        #pragma unroll
        for (int i = 0; i < 4; i++) {
            int m = n - 2 * i;
            mk[i] = (m >= 2) ? 0xFFFFFFFFu : ((m == 1) ? 0xFFFFu : 0u);
        }
        if (ks1 == 2) {
            #pragma unroll
            for (int i = 0; i < 4; i++) { B2u[i] &= mk[i]; B3u[i] &= mk[i]; }
        } else {
            #pragma unroll
            for (int i = 0; i < 4; i++) { B0u[i] &= mk[i]; B1u[i] &= mk[i]; }
        }
    }
    const float xv = x[(size_t)(b0 + (tid & 127)) * 64 + keff];   // RQS input (f32 exact)

    __syncthreads();   // LDS blob resident

    // ---- GEMM1: H1 = tanh(W1 X^T + b1), K truncated by tril ----
    {
        f4 acc[4][2];
        #pragma unroll
        for (int mt = 0; mt < 4; mt++) {
            f4 bv = *(const f4*)&b1s[mt * 16 + q * 4];
            acc[mt][0] = bv; acc[mt][1] = bv;
        }
        {
            s8 bx0 = __builtin_bit_cast(s8, B0u), bx1 = __builtin_bit_cast(s8, B1u);
            #pragma unroll
            for (int mt = 0; mt < 4; mt++) {
                acc[mt][0] = __builtin_amdgcn_mfma_f32_16x16x32_bf16(aw1[0][mt], bx0, acc[mt][0], 0, 0, 0);
                acc[mt][1] = __builtin_amdgcn_mfma_f32_16x16x32_bf16(aw1[0][mt], bx1, acc[mt][1], 0, 0, 0);
            }
        }
        if (ks1 == 2) {
            s8 bx0 = __builtin_bit_cast(s8, B2u), bx1 = __builtin_bit_cast(s8, B3u);
            #pragma unroll
            for (int mt = 0; mt < 4; mt++) {
                acc[mt][0] = __builtin_amdgcn_mfma_f32_16x16x32_bf16(aw1[1][mt], bx0, acc[mt][0], 0, 0, 0);
                acc[mt][1] = __builtin_amdgcn_mfma_f32_16x16x32_bf16(aw1[1][mt], bx1, acc[mt][1], 0, 0, 0);
            }
        }
        #pragma unroll
        for (int mt = 0; mt < 4; mt++)
            #pragma unroll
            for (int nt = 0; nt < 2; nt++) {
                f4 a = acc[mt][nt];
                unsigned long long w = (unsigned long long)pk2(fast_tanh(a[0]), fast_tanh(a[1]))
                    | ((unsigned long long)pk2(fast_tanh(a[2]), fast_tanh(a[3])) << 32);
                *(unsigned long long*)&Hs[(mbase + nt * 16 + c) * XS + mt * 16 + q * 4] = w;
            }
    }

    // ---- GEMM2: H2 = tanh(W2 H1^T + b2), wave-own rows, no barrier ----
    {
        f4 acc[4][2];
        #pragma unroll
        for (int mt = 0; mt < 4; mt++) {
            f4 bv = *(const f4*)&b2s[mt * 16 + q * 4];
            acc[mt][0] = bv; acc[mt][1] = bv;
        }
        #pragma unroll
        for (int ks = 0; ks < 2; ks++) {
            s8 bh0 = *(const s8*)&Hs[(mbase + c) * XS + ks * 32 + q * 8];
            s8 bh1 = *(const s8*)&Hs[(mbase + 16 + c) * XS + ks * 32 + q * 8];
            const int sb = ((ks * 4 + q) ^ c7) * 8;
            #pragma unroll
            for (int mt = 0; mt < 4; mt++) {
                s8 aw = *(const s8*)&W2s[(mt * 16 + c) * 64 + sb];
                acc[mt][0] = __builtin_amdgcn_mfma_f32_16x16x32_bf16(aw, bh0, acc[mt][0], 0, 0, 0);
                acc[mt][1] = __builtin_amdgcn_mfma_f32_16x16x32_bf16(aw, bh1, acc[mt][1], 0, 0, 0);
            }
        }
        #pragma unroll
        for (int mt = 0; mt < 4; mt++)
            #pragma unroll
            for (int nt = 0; nt < 2; nt++) {
                f4 a = acc[mt][nt];
                unsigned long long w = (unsigned long long)pk2(fast_tanh(a[0]), fast_tanh(a[1]))
                    | ((unsigned long long)pk2(fast_tanh(a[2]), fast_tanh(a[3])) << 32);
                *(unsigned long long*)&Hs[(mbase + nt * 16 + c) * XS + mt * 16 + q * 4] = w;
            }
    }

    // ---- GEMM3: OUT = W3 H2^T + b3 (23 outs padded 32, along m) ----
    {
        f4 acc3[2][2];
        #pragma unroll
        for (int mt = 0; mt < 2; mt++) {
            f4 bv = *(const f4*)&b3s[mt * 16 + q * 4];
            acc3[mt][0] = bv; acc3[mt][1] = bv;
        }
        #pragma unroll
        for (int ks = 0; ks < 2; ks++) {
            s8 bh0 = *(const s8*)&Hs[(mbase + c) * XS + ks * 32 + q * 8];
            s8 bh1 = *(const s8*)&Hs[(mbase + 16 + c) * XS + ks * 32 + q * 8];
            const int sb = ((ks * 4 + q) ^ c7) * 8;
            #pragma unroll
            for (int mt = 0; mt < 2; mt++) {
                s8 aw = *(const s8*)&W3s[(mt * 16 + c) * 64 + sb];
                acc3[mt][0] = __builtin_amdgcn_mfma_f32_16x16x32_bf16(aw, bh0, acc3[mt][0], 0, 0, 0);
                acc3[mt][1] = __builtin_amdgcn_mfma_f32_16x16x32_bf16(aw, bh1, acc3[mt][1], 0, 0, 0);
            }
        }
        // Ps overlay on wave-own Hs rows (h2 dead): b128 writes
        #pragma unroll
        for (int mt = 0; mt < 2; mt++)
            #pragma unroll
            for (int nt = 0; nt < 2; nt++)
                *(f4*)&PsF[(mbase + nt * 16 + c) * 36 + mt * 16 + q * 4] = acc3[mt][nt];
    }
    __syncthreads();   // Ps complete across waves

    // ---- fused RQS: one thread per row; z in final layout; ld atomic ----
    if (tid < BM) {
        float p[23];
        #pragma unroll
        for (int j = 0; j < 23; j++) p[j] = PsF[tid * 36 + j];
        float zv, lv;
        rqs_eval(p, xv, zv, lv);
        z[(size_t)(b0 + tid) * 64 + keff] = zv;
        unsafeAtomicAdd(ld + b0 + tid, lv);
    }
}

extern "C" void kernel_launch(void* const* d_in, const int* in_sizes, int n_in,
                              void* d_out, int out_size, void* d_ws, size_t ws_size,
                              hipStream_t stream)
{
    const float* x  = (const float*)d_in[0];
    const float* ip = (const float*)d_in[1];
    const float* W1 = (const float*)d_in[2];
    const float* b1 = (const float*)d_in[3];
    const float* W2 = (const float*)d_in[4];
    const float* b2 = (const float*)d_in[5];
    const float* W3 = (const float*)d_in[6];
    const float* b3 = (const float*)d_in[7];

    float* z  = (float*)d_out;                  // [B][64]
    float* ld = z + (size_t)BATCH * 64;         // [B]

    unsigned char* blobG = (unsigned char*)d_ws;   // 63 * 21504 B

    prep_kernel<<<LAYERS, 256, 0, stream>>>(W1, W2, W3, b1, b2, b3, blobG);
    hipMemsetAsync(ld, 0, BATCH * sizeof(float), stream);   // atomic accumulator base
    mlp_rqs_kernel<<<dim3(BATCH / BM, LAYERS + 1), 256, 0, stream>>>(
        x, ip, blobG, z, ld);
}